// Round 1
// baseline (348.849 us; speedup 1.0000x reference)
//
#include <hip/hip_runtime.h>

// TestEBCModel: jagged embedding gather + SUM pool (T=4,B=8192,L=50,VOCAB=100000,D=128)
// followed by 3 stacked Linear(D,D) with no activation.
// Affine fold: M = W1^T W2^T W3^T, c = (b1 W2^T + b2) W3^T + b3; fused kernel does
// pool + single matvec per row.
// R4: ROWS=16 / grid=2048 with __launch_bounds__(256,8) -> exactly 1 residency round
// (8 blocks/CU x 256 CU). Gather upgraded to float4/lane half-split: lanes 0-31 pool
// even list positions, lanes 32-63 odd, 1KB (2 rows) per wave-load (half the VMEM
// instrs of the float2 scheme), combined via 4x shfl_xor(32). Indices pre-shifted
// to byte offsets at staging. Phase 2 does 2 cols x 4 rows per thread (float2 M
// loads, broadcast LDS reads).

#define T_ 4
#define B_ 8192
#define L_ 50
#define VOCAB_ 100000
#define D_ 128
#define ROWS 16        // bags per block in fused kernel
#define NBAGS (T_ * B_)

// ws layout (floats): M[16384] | c[128]
#define WS_M  0
#define WS_C  16384

// ---- merged combine: M = (W1^T W2^T) W3^T ; c = ((b1 W2^T + b2)) W3^T + b3 ----
// blocks 0..127 compute M row i; block 128 computes c. Branch is block-uniform.
__global__ __launch_bounds__(128) void combine(const float* __restrict__ W1,
                                               const float* __restrict__ W2,
                                               const float* __restrict__ W3,
                                               const float* __restrict__ b1,
                                               const float* __restrict__ b2,
                                               const float* __restrict__ b3,
                                               float* __restrict__ ws) {
  __shared__ float a1[D_];
  const int j = threadIdx.x;
  const int i = blockIdx.x;
  if (i < D_) {
    // a1[m] = A1[i][m] = sum_k W1[k][i] * W2[m][k]   (thread j computes m=j)
    float acc = 0.f;
    for (int k = 0; k < D_; ++k)
      acc += W1[k * D_ + i] * W2[j * D_ + k];
    a1[j] = acc;
    __syncthreads();
    // M[i][j] = sum_m a1[m] * W3[j][m]
    float m = 0.f;
    for (int k = 0; k < D_; ++k)
      m += a1[k] * W3[j * D_ + k];
    ws[WS_M + i * D_ + j] = m;
  } else {
    // c1[j] = b2[j] + sum_k b1[k] W2[j][k] ; c[j] = b3[j] + sum_m c1[m] W3[j][m]
    float c1 = b2[j];
    for (int k = 0; k < D_; ++k)
      c1 += b1[k] * W2[j * D_ + k];
    a1[j] = c1;
    __syncthreads();
    float c = b3[j];
    for (int k = 0; k < D_; ++k)
      c += a1[k] * W3[j * D_ + k];
    ws[WS_C + j] = c;
  }
}

// ---- fused: pool ROWS bags (dynamic wave->bag), then out = pooled @ M + c ----
__global__ __launch_bounds__(256, 8) void fused(const int* __restrict__ indices,
                                                const int* __restrict__ lengths,
                                                const float* __restrict__ tables,
                                                const float* __restrict__ ws,
                                                float* __restrict__ out) {
  __shared__ __align__(16) float pooled_sh[ROWS][D_];  // row-major: b128 writes, broadcast reads
  __shared__ int off_sh[ROWS][L_];                     // pre-shifted byte offsets (idx<<9)
  __shared__ int len_sh[ROWS];
  __shared__ int bag_ctr;

  const int tid = threadIdx.x;
  const int g0  = blockIdx.x * ROWS;

  if (tid == 0) bag_ctr = 0;
  for (int k = tid; k < ROWS * L_; k += 256)
    off_sh[k / L_][k % L_] = indices[g0 * L_ + k] << 9;  // row byte offset
  if (tid < ROWS) len_sh[tid] = lengths[g0 + tid];
  __syncthreads();

  // phase 1: waves pull bags from the LDS counter until exhausted.
  // float4 per lane, half-split: lanes 0-31 pool even positions, 32-63 odd.
  // One wave-load = 1KB = 2 embedding rows; unroll 8 positions = 4 loads in flight.
  {
    const int lane = tid & 63;
    const int half = lane >> 5;            // 0: even positions, 1: odd positions
    const int d0   = (lane & 31) * 4;      // 4 floats per lane, 32 lanes span D=128
    const int t    = g0 >> 13;             // table id; block never spans tables (16 | 8192)
    const char* __restrict__ tab =
        (const char*)(tables + (size_t)t * (VOCAB_ * D_) + d0);

    for (;;) {
      int pos = 0;
      if (lane == 0) pos = atomicAdd(&bag_ctr, 1);
      pos = __shfl(pos, 0, 64);
      if (pos >= ROWS) break;
      const int len = len_sh[pos];
      const int* __restrict__ il = off_sh[pos];
      float ax = 0.f, ay = 0.f, az = 0.f, aw = 0.f;
      int l = 0;
      for (; l + 7 < len; l += 8) {
        const int o0 = il[l + 0 + half];   // 2-way LDS broadcast (free)
        const int o1 = il[l + 2 + half];
        const int o2 = il[l + 4 + half];
        const int o3 = il[l + 6 + half];
        const float4 v0 = *(const float4*)(tab + o0);
        const float4 v1 = *(const float4*)(tab + o1);
        const float4 v2 = *(const float4*)(tab + o2);
        const float4 v3 = *(const float4*)(tab + o3);
        ax += v0.x; ay += v0.y; az += v0.z; aw += v0.w;
        ax += v1.x; ay += v1.y; az += v1.z; aw += v1.w;
        ax += v2.x; ay += v2.y; az += v2.z; aw += v2.w;
        ax += v3.x; ay += v3.y; az += v3.z; aw += v3.w;
      }
      for (; l + 1 < len; l += 2) {
        const float4 v = *(const float4*)(tab + il[l + half]);
        ax += v.x; ay += v.y; az += v.z; aw += v.w;
      }
      if (l < len && half == 0) {          // odd tail: half 0 covers it alone
        const float4 v = *(const float4*)(tab + il[l]);
        ax += v.x; ay += v.y; az += v.z; aw += v.w;
      }
      // fold the two halves together; lanes 0-31 then own the full row sum
      ax += __shfl_xor(ax, 32, 64);
      ay += __shfl_xor(ay, 32, 64);
      az += __shfl_xor(az, 32, 64);
      aw += __shfl_xor(aw, 32, 64);
      if (half == 0)
        *(float4*)&pooled_sh[pos][d0] = make_float4(ax, ay, az, aw);  // contiguous b128
    }
  }
  __syncthreads();

  // phase 2: out[g0+r][j] = c[j] + sum_i pooled[r][i] * M[i][j]
  // 2 cols x 4 rows per thread: per i, 1 float2 M load (wave = 512B coalesced,
  // L2-hot), 4 broadcast LDS reads, 8 FMAs.
  const int jc = (tid & 63) * 2;           // column pair
  const int rh = (tid >> 6) * 4;           // rows rh..rh+3 (wave-uniform)
  const float* __restrict__ Mg = ws + WS_M;
  const float2 c2 = *(const float2*)(ws + WS_C + jc);
  float2 a0 = c2, a1 = c2, a2 = c2, a3 = c2;
#pragma unroll 4
  for (int i = 0; i < D_; ++i) {
    const float2 m = *(const float2*)(Mg + i * D_ + jc);
    const float p0 = pooled_sh[rh + 0][i];
    const float p1 = pooled_sh[rh + 1][i];
    const float p2 = pooled_sh[rh + 2][i];
    const float p3 = pooled_sh[rh + 3][i];
    a0.x += p0 * m.x; a0.y += p0 * m.y;
    a1.x += p1 * m.x; a1.y += p1 * m.y;
    a2.x += p2 * m.x; a2.y += p2 * m.y;
    a3.x += p3 * m.x; a3.y += p3 * m.y;
  }
  *(float2*)&out[(size_t)(g0 + rh + 0) * D_ + jc] = a0;
  *(float2*)&out[(size_t)(g0 + rh + 1) * D_ + jc] = a1;
  *(float2*)&out[(size_t)(g0 + rh + 2) * D_ + jc] = a2;
  *(float2*)&out[(size_t)(g0 + rh + 3) * D_ + jc] = a3;
}

extern "C" void kernel_launch(void* const* d_in, const int* in_sizes, int n_in,
                              void* d_out, int out_size, void* d_ws, size_t ws_size,
                              hipStream_t stream) {
  const int*   indices = (const int*)d_in[0];
  const int*   lengths = (const int*)d_in[1];
  const float* tables  = (const float*)d_in[2];
  const float* W1      = (const float*)d_in[3];
  const float* b1      = (const float*)d_in[4];
  const float* W2      = (const float*)d_in[5];
  const float* b2      = (const float*)d_in[6];
  const float* W3      = (const float*)d_in[7];
  const float* b3      = (const float*)d_in[8];
  float*       out     = (float*)d_out;
  float*       ws      = (float*)d_ws;

  combine<<<D_ + 1, D_, 0, stream>>>(W1, W2, W3, b1, b2, b3, ws);
  fused<<<NBAGS / ROWS, 256, 0, stream>>>(indices, lengths, tables, ws, out);
}